// Round 4
// baseline (238.663 us; speedup 1.0000x reference)
//
#include <hip/hip_runtime.h>

#define T_DIM 512
#define B_DIM 16
#define D_DIM 1024
#define WINR  16
#define NW    33                  // 2*WINR+1
#define TT    32                  // t-rows per attention block
#define NR    (TT + 2 * WINR)     // 64 source rows per block

typedef float f32x2 __attribute__((ext_vector_type(2)));
typedef float f32x4 __attribute__((ext_vector_type(4)));

// ---------------- Kernel A: c[t,b] = dot(x[t,b,:], w_seq) ----------------
// One wave per (t,b) pair; 4 waves per block. Reads x exactly once (32 MiB).
__global__ __launch_bounds__(256) void calc_c_kernel(const float* __restrict__ x,
                                                     const float* __restrict__ w,
                                                     float* __restrict__ c) {
    const int wave = threadIdx.x >> 6;
    const int lane = threadIdx.x & 63;
    const int pair = blockIdx.x * 4 + wave;           // pair = t*B + b
    const f32x4* x4 = reinterpret_cast<const f32x4*>(x + (size_t)pair * D_DIM);
    const f32x4* w4 = reinterpret_cast<const f32x4*>(w + D_DIM);  // w_seq
    float acc = 0.f;
    #pragma unroll
    for (int i = 0; i < 4; ++i) {
        f32x4 xv = x4[i * 64 + lane];
        f32x4 wv = w4[i * 64 + lane];
        acc += xv.x * wv.x + xv.y * wv.y + xv.z * wv.z + xv.w * wv.w;
    }
    #pragma unroll
    for (int off = 32; off; off >>= 1) acc += __shfl_xor(acc, off, 64);
    if (lane == 0) c[pair] = acc;
}

// ------------- Kernel B: windowed softmax + gather + concat -------------
// Block = (b, 32 t-rows, D-half). 256 threads, thread owns float2.
// dd[i][j]: weight of source row (t0-16+i) for output row (t0+j); 0 outside window.
// (a[t,b] and bias are constant along the softmax axis -> cancel.)
__global__ __launch_bounds__(256, 4) void attn_kernel(const float* __restrict__ x,
                                                      const float* __restrict__ c,
                                                      float* __restrict__ out) {
    __shared__ __align__(16) float dd[NR][TT];        // 8 KiB

    const int half = blockIdx.x & 1;
    const int b    = (blockIdx.x >> 1) & (B_DIM - 1);
    const int t0   = (blockIdx.x >> 5) * TT;
    const int tid  = threadIdx.x;
    const int d0   = half * (D_DIM / 2) + tid * 2;
    const size_t rs = (size_t)B_DIM * D_DIM;          // x t-stride (floats)

    // ---- zero dd ----
    {
        float* ddf = &dd[0][0];
        #pragma unroll
        for (int i = 0; i < (NR * TT) / 256; ++i) ddf[tid + i * 256] = 0.f;
    }
    __syncthreads();

    // ---- phase 1: 32 threads compute softmax rows into diagonal layout ----
    if (tid < TT) {
        const int t = t0 + tid;
        float sc[NW];
        float m = -1e30f;
        #pragma unroll
        for (int ww = 0; ww < NW; ++ww) {
            const int s = t - WINR + ww;
            const float v = (s >= 0 && s < T_DIM) ? c[s * B_DIM + b] : -1e30f;
            sc[ww] = v;
            m = fmaxf(m, v);
        }
        float sum = 0.f;
        #pragma unroll
        for (int ww = 0; ww < NW; ++ww) {
            const float e = (sc[ww] > -1e29f) ? __expf(sc[ww] - m) : 0.f;
            sc[ww] = e;
            sum += e;
        }
        const float inv = 1.f / sum;
        #pragma unroll
        for (int ww = 0; ww < NW; ++ww) dd[tid + ww][tid] = sc[ww] * inv;
    }
    __syncthreads();

    // ---- phase 2: stream 64 source rows; each read once per block ----
    f32x2 acc[TT];
    #pragma unroll
    for (int j = 0; j < TT; ++j) acc[j] = (f32x2){0.f, 0.f};

    const float* xb = x + (size_t)b * D_DIM + d0;
    float* ob = out + (size_t)b * 2 * D_DIM + d0;

    #pragma unroll 4
    for (int ss = -WINR; ss < TT + WINR; ++ss) {
        const int s = t0 + ss;
        f32x2 xs = (f32x2){0.f, 0.f};
        if ((unsigned)s < (unsigned)T_DIM) {
            xs = *reinterpret_cast<const f32x2*>(xb + (size_t)s * rs);
        }
        // center row doubles as the x-copy half of the output
        if ((unsigned)ss < (unsigned)TT) {
            __builtin_nontemporal_store(xs,
                reinterpret_cast<f32x2*>(ob + (size_t)(t0 + ss) * 2 * rs));
        }
        const f32x4* dr = reinterpret_cast<const f32x4*>(dd[ss + WINR]);

        #define FMA2(j, pv) \
            acc[j].x += (pv) * xs.x; acc[j].y += (pv) * xs.y;

        {   // j = 0..15
            const f32x4 q0 = dr[0], q1 = dr[1], q2 = dr[2], q3 = dr[3];
            FMA2(0,  q0.x) FMA2(1,  q0.y) FMA2(2,  q0.z) FMA2(3,  q0.w)
            FMA2(4,  q1.x) FMA2(5,  q1.y) FMA2(6,  q1.z) FMA2(7,  q1.w)
            FMA2(8,  q2.x) FMA2(9,  q2.y) FMA2(10, q2.z) FMA2(11, q2.w)
            FMA2(12, q3.x) FMA2(13, q3.y) FMA2(14, q3.z) FMA2(15, q3.w)
        }
        {   // j = 16..31
            const f32x4 q4 = dr[4], q5 = dr[5], q6 = dr[6], q7 = dr[7];
            FMA2(16, q4.x) FMA2(17, q4.y) FMA2(18, q4.z) FMA2(19, q4.w)
            FMA2(20, q5.x) FMA2(21, q5.y) FMA2(22, q5.z) FMA2(23, q5.w)
            FMA2(24, q6.x) FMA2(25, q6.y) FMA2(26, q6.z) FMA2(27, q6.w)
            FMA2(28, q7.x) FMA2(29, q7.y) FMA2(30, q7.z) FMA2(31, q7.w)
        }
        #undef FMA2
    }

    // ---- phase 3: attention half ----
    #pragma unroll
    for (int j = 0; j < TT; ++j) {
        __builtin_nontemporal_store(acc[j],
            reinterpret_cast<f32x2*>(ob + (size_t)(t0 + j) * 2 * rs + D_DIM));
    }
}

extern "C" void kernel_launch(void* const* d_in, const int* in_sizes, int n_in,
                              void* d_out, int out_size, void* d_ws, size_t ws_size,
                              hipStream_t stream) {
    const float* x = (const float*)d_in[0];
    const float* w = (const float*)d_in[1];
    float* c   = (float*)d_ws;                 // T*B floats = 32 KiB scratch
    float* out = (float*)d_out;

    calc_c_kernel<<<(T_DIM * B_DIM) / 4, 256, 0, stream>>>(x, w, c);
    attn_kernel<<<(T_DIM / TT) * B_DIM * 2, 256, 0, stream>>>(x, c, out);
}

// Round 6
// 112.954 us; speedup vs baseline: 2.1129x; 2.1129x over previous
//
#include <hip/hip_runtime.h>

#define T_DIM 512
#define B_DIM 16
#define D_DIM 1024
#define WINR  16
#define NW    33                  // 2*WINR+1
#define TT    16                  // t-rows per attention block
#define NR    (TT + 2 * WINR)     // 48 source rows per block

typedef float f32x2 __attribute__((ext_vector_type(2)));
typedef float f32x4 __attribute__((ext_vector_type(4)));

// ---------------- Kernel A: c[t,b] = dot(x[t,b,:], w_seq) ----------------
// One wave per (t,b) pair; 4 waves per block. Reads x exactly once (32 MiB).
__global__ __launch_bounds__(256) void calc_c_kernel(const float* __restrict__ x,
                                                     const float* __restrict__ w,
                                                     float* __restrict__ c) {
    const int wave = threadIdx.x >> 6;
    const int lane = threadIdx.x & 63;
    const int pair = blockIdx.x * 4 + wave;           // pair = t*B + b
    const f32x4* x4 = reinterpret_cast<const f32x4*>(x + (size_t)pair * D_DIM);
    const f32x4* w4 = reinterpret_cast<const f32x4*>(w + D_DIM);  // w_seq
    float acc = 0.f;
    #pragma unroll
    for (int i = 0; i < 4; ++i) {
        f32x4 xv = x4[i * 64 + lane];
        f32x4 wv = w4[i * 64 + lane];
        acc += xv.x * wv.x + xv.y * wv.y + xv.z * wv.z + xv.w * wv.w;
    }
    #pragma unroll
    for (int off = 32; off; off >>= 1) acc += __shfl_xor(acc, off, 64);
    if (lane == 0) c[pair] = acc;
}

// ------------- Kernel B: windowed softmax + gather + concat -------------
// Block = (b, 16 t-rows, D-half). 256 threads, thread owns float2 at d0.
// dd[i][j]: weight of source row (t0-16+i) for output row (t0+j); 0 outside window.
// (a[t,b] and bias are constant along the softmax axis -> cancel.)
// acc = 16 x f32x2 = 32 VGPRs; total pressure ~80 -> no spills, 16 waves/CU.
__global__ __launch_bounds__(256) void attn_kernel(const float* __restrict__ x,
                                                   const float* __restrict__ c,
                                                   float* __restrict__ out) {
    __shared__ __align__(16) float dd[NR][TT];        // 3 KiB

    const int half = blockIdx.x & 1;
    const int b    = (blockIdx.x >> 1) & (B_DIM - 1);
    const int t0   = (blockIdx.x >> 5) * TT;
    const int tid  = threadIdx.x;
    const int d0   = half * (D_DIM / 2) + tid * 2;
    const size_t rs = (size_t)B_DIM * D_DIM;          // x t-stride (floats)

    // ---- zero dd ----
    {
        float* ddf = &dd[0][0];
        #pragma unroll
        for (int i = 0; i < (NR * TT) / 256; ++i) ddf[tid + i * 256] = 0.f;
    }
    __syncthreads();

    // ---- phase 1: 16 threads compute softmax rows into diagonal layout ----
    if (tid < TT) {
        const int t = t0 + tid;
        float sc[NW];
        float m = -1e30f;
        #pragma unroll
        for (int ww = 0; ww < NW; ++ww) {
            const int s = t - WINR + ww;
            const float v = (s >= 0 && s < T_DIM) ? c[s * B_DIM + b] : -1e30f;
            sc[ww] = v;
            m = fmaxf(m, v);
        }
        float sum = 0.f;
        #pragma unroll
        for (int ww = 0; ww < NW; ++ww) {
            const float e = (sc[ww] > -1e29f) ? __expf(sc[ww] - m) : 0.f;
            sc[ww] = e;
            sum += e;
        }
        const float inv = 1.f / sum;
        #pragma unroll
        for (int ww = 0; ww < NW; ++ww) dd[tid + ww][tid] = sc[ww] * inv;
    }
    __syncthreads();

    // ---- phase 2: stream 48 source rows; each read once per block ----
    f32x2 acc[TT];
    #pragma unroll
    for (int j = 0; j < TT; ++j) acc[j] = (f32x2){0.f, 0.f};

    const float* xb = x + (size_t)b * D_DIM + d0;
    float* ob = out + (size_t)b * 2 * D_DIM + d0;

    #pragma unroll 2
    for (int ss = -WINR; ss < TT + WINR; ++ss) {
        const int s = t0 + ss;
        f32x2 xs = (f32x2){0.f, 0.f};
        if ((unsigned)s < (unsigned)T_DIM) {
            xs = *reinterpret_cast<const f32x2*>(xb + (size_t)s * rs);
        }
        // center row doubles as the x-copy half of the output
        if ((unsigned)ss < (unsigned)TT) {
            *reinterpret_cast<f32x2*>(ob + (size_t)(t0 + ss) * 2 * rs) = xs;
        }
        const f32x4* dr = reinterpret_cast<const f32x4*>(dd[ss + WINR]);
        const f32x4 q0 = dr[0], q1 = dr[1], q2 = dr[2], q3 = dr[3];

        #define FMA2(j, pv) \
            acc[j].x += (pv) * xs.x; acc[j].y += (pv) * xs.y;
        FMA2(0,  q0.x) FMA2(1,  q0.y) FMA2(2,  q0.z) FMA2(3,  q0.w)
        FMA2(4,  q1.x) FMA2(5,  q1.y) FMA2(6,  q1.z) FMA2(7,  q1.w)
        FMA2(8,  q2.x) FMA2(9,  q2.y) FMA2(10, q2.z) FMA2(11, q2.w)
        FMA2(12, q3.x) FMA2(13, q3.y) FMA2(14, q3.z) FMA2(15, q3.w)
        #undef FMA2
    }

    // ---- phase 3: attention half ----
    #pragma unroll
    for (int j = 0; j < TT; ++j) {
        *reinterpret_cast<f32x2*>(ob + (size_t)(t0 + j) * 2 * rs + D_DIM) = acc[j];
    }
}

extern "C" void kernel_launch(void* const* d_in, const int* in_sizes, int n_in,
                              void* d_out, int out_size, void* d_ws, size_t ws_size,
                              hipStream_t stream) {
    const float* x = (const float*)d_in[0];
    const float* w = (const float*)d_in[1];
    float* c   = (float*)d_ws;                 // T*B floats = 32 KiB scratch
    float* out = (float*)d_out;

    calc_c_kernel<<<(T_DIM * B_DIM) / 4, 256, 0, stream>>>(x, w, c);
    attn_kernel<<<(T_DIM / TT) * B_DIM * 2, 256, 0, stream>>>(x, c, out);
}